// Round 2
// baseline (22255.841 us; speedup 1.0000x reference)
//
#include <hip/hip_runtime.h>

// RNNModel: B=64, T=512, I=256, H=1024, L=4 + FC(H->1).
// Round 1: fused-projection multi-launch recurrence.
//   h_t = tanh(W_ih * in_t + W_hh * h_{t-1} + b_ih + b_hh)
// computed per step as two MFMA K-loops with fp32 C-init = bias sum.
// Workspace cut to ~148 MB (round 0 used 276 MB unchecked -> possible OOB fault).
//
// Numerics: fp16 A/B operands, fp32 accumulation. Per-step error gain
// ||tanh'||*||W_hh|| ~ 0.52 < 1 => steady-state error ~1e-4, predicted output
// absmax ~5e-4 << 4.375e-3 threshold.

typedef _Float16 f16;
typedef _Float16 f16x8 __attribute__((ext_vector_type(8)));
typedef _Float16 f16x4 __attribute__((ext_vector_type(4)));
typedef float    f32x4 __attribute__((ext_vector_type(4)));

#define BB 64
#define TT 512
#define II 256
#define HH 1024

// ---------------- fp32 -> fp16 convert (vectorized, grid-stride) -------------
__global__ __launch_bounds__(256) void cvt_kernel(const float* __restrict__ in,
                                                  f16* __restrict__ out, int n4) {
  int stride = gridDim.x * blockDim.x;
  for (int i = blockIdx.x * blockDim.x + threadIdx.x; i < n4; i += stride) {
    float4 v = reinterpret_cast<const float4*>(in)[i];
    f16x4 h = { (f16)v.x, (f16)v.y, (f16)v.z, (f16)v.w };
    reinterpret_cast<f16x4*>(out)[i] = h;
  }
}

__global__ __launch_bounds__(256) void bsum_kernel(const float* __restrict__ a,
                                                   const float* __restrict__ b,
                                                   float* __restrict__ o) {
  int i = blockIdx.x * blockDim.x + threadIdx.x;
  if (i < HH) o[i] = a[i] + b[i];
}

// ---------------- fused recurrence step -------------------------------------
// grid = 256 blocks (4 b-groups x 64 r-groups) x 64 threads (1 wave).
// Each wave computes one 16(batch) x 16(feature) C tile:
//   C = bsum + in[t] @ W_ih^T + h[t-1] @ W_hh^T ; h[t] = tanh(C)
// MFMA 16x16x32_f16 layouts (m89/m120-verified):
//   A: lane holds A[m=lane&15][k=(lane>>4)*8+j]   (16B contiguous)
//   B: lane holds B[k=(lane>>4)*8+j][n=lane&15]   (row n of W, 16B contiguous)
//   C/D: lane holds C[row=(lane>>4)*4+i][col=lane&15]
__global__ __launch_bounds__(64) void step_kernel(
    const f16* __restrict__ in,   // prev-layer seq [B][T][Kin] (or x16)
    int Kin,
    f16* __restrict__ hs,         // own-layer seq [B][T][H]; read t-1, write t
    const f16* __restrict__ wih,  // [H][Kin] row-major
    const f16* __restrict__ whh,  // [H][H] row-major
    const float* __restrict__ bsum,
    int t) {
  const int lane = threadIdx.x & 63;
  const int rg = blockIdx.x & 63;
  const int bg = blockIdx.x >> 6;
  const int b0 = bg * 16, r0 = rg * 16;
  const int l15 = lane & 15, quad = lane >> 4;

  float bv = bsum[r0 + l15];
  f32x4 c0 = { bv, bv, bv, bv };
  f32x4 c1 = {}, c2 = {}, c3 = {};

  // ---- input projection: in[t] @ W_ih^T (two interleaved chains) ----
  {
    const f16* ap = in + ((size_t)(b0 + l15) * TT + t) * Kin + quad * 8;
    const f16* bp = wih + (size_t)(r0 + l15) * Kin + quad * 8;
#pragma unroll 4
    for (int k0 = 0; k0 < Kin; k0 += 64) {
      f16x8 a0 = *reinterpret_cast<const f16x8*>(ap + k0);
      f16x8 w0 = *reinterpret_cast<const f16x8*>(bp + k0);
      f16x8 a1 = *reinterpret_cast<const f16x8*>(ap + k0 + 32);
      f16x8 w1 = *reinterpret_cast<const f16x8*>(bp + k0 + 32);
      c0 = __builtin_amdgcn_mfma_f32_16x16x32_f16(a0, w0, c0, 0, 0, 0);
      c1 = __builtin_amdgcn_mfma_f32_16x16x32_f16(a1, w1, c1, 0, 0, 0);
    }
  }

  // ---- recurrence: h[t-1] @ W_hh^T ----
  if (t > 0) {
    const f16* ap = hs + ((size_t)(b0 + l15) * TT + (t - 1)) * HH + quad * 8;
    const f16* bp = whh + (size_t)(r0 + l15) * HH + quad * 8;
#pragma unroll 4
    for (int k0 = 0; k0 < HH; k0 += 64) {
      f16x8 a0 = *reinterpret_cast<const f16x8*>(ap + k0);
      f16x8 w0 = *reinterpret_cast<const f16x8*>(bp + k0);
      f16x8 a1 = *reinterpret_cast<const f16x8*>(ap + k0 + 32);
      f16x8 w1 = *reinterpret_cast<const f16x8*>(bp + k0 + 32);
      c2 = __builtin_amdgcn_mfma_f32_16x16x32_f16(a0, w0, c2, 0, 0, 0);
      c3 = __builtin_amdgcn_mfma_f32_16x16x32_f16(a1, w1, c3, 0, 0, 0);
    }
  }

  f32x4 e = (c0 + c1) + (c2 + c3);
#pragma unroll
  for (int i = 0; i < 4; ++i) {
    float h = tanhf(e[i]);
    hs[((size_t)(b0 + quad * 4 + i) * TT + t) * HH + r0 + l15] = (f16)h;
  }
}

// ---------------- final FC: out[m] = hs[m][:] . fc_w + fc_b ------------------
__global__ __launch_bounds__(256) void fc_kernel(const f16* __restrict__ hs,
                                                 const float* __restrict__ fcw,
                                                 const float* __restrict__ fcb,
                                                 float* __restrict__ out) {
  const int lane = threadIdx.x & 63;
  const int m = blockIdx.x * 4 + (threadIdx.x >> 6);
  const f16* hp = hs + (size_t)m * HH;
  f16x8 v1 = *reinterpret_cast<const f16x8*>(hp + lane * 8);
  f16x8 v2 = *reinterpret_cast<const f16x8*>(hp + 512 + lane * 8);
  float acc = 0.f;
#pragma unroll
  for (int j = 0; j < 8; ++j) {
    acc += (float)v1[j] * fcw[lane * 8 + j];
    acc += (float)v2[j] * fcw[512 + lane * 8 + j];
  }
#pragma unroll
  for (int off = 32; off > 0; off >>= 1) acc += __shfl_down(acc, off, 64);
  if (lane == 0) out[m] = acc + fcb[0];
}

extern "C" void kernel_launch(void* const* d_in, const int* in_sizes, int n_in,
                              void* d_out, int out_size, void* d_ws, size_t ws_size,
                              hipStream_t stream) {
  const float* x   = (const float*)d_in[0];
  const float* fcw = (const float*)d_in[17];
  const float* fcb = (const float*)d_in[18];

  char* ws = (char*)d_ws;
  size_t off = 0;
  auto alloc = [&](size_t bytes) -> void* {
    void* p = ws + off;
    off += (bytes + 255) & ~(size_t)255;
    return p;
  };
  f16*   x16   = (f16*)alloc((size_t)BB * TT * II * 2);   //  16 MB
  f16*   hsA   = (f16*)alloc((size_t)BB * TT * HH * 2);   //  64 MB
  f16*   hsB   = (f16*)alloc((size_t)BB * TT * HH * 2);   //  64 MB
  f16*   w16ih = (f16*)alloc((size_t)HH * HH * 2);        //   2 MB
  f16*   w16hh = (f16*)alloc((size_t)HH * HH * 2);        //   2 MB
  float* bsum  = (float*)alloc((size_t)HH * 4);           // total ~148 MB

  cvt_kernel<<<1024, 256, 0, stream>>>(x, x16, BB * TT * II / 4);

  const f16* in_seq = x16;
  int Kin = II;
  f16* hs_bufs[2] = { hsA, hsB };
  for (int l = 0; l < 4; ++l) {
    const float* Wih = (const float*)d_in[1 + 4 * l];
    const float* Whh = (const float*)d_in[2 + 4 * l];
    const float* bih = (const float*)d_in[3 + 4 * l];
    const float* bhh = (const float*)d_in[4 + 4 * l];

    cvt_kernel<<<1024, 256, 0, stream>>>(Wih, w16ih, HH * Kin / 4);
    cvt_kernel<<<1024, 256, 0, stream>>>(Whh, w16hh, HH * HH / 4);
    bsum_kernel<<<4, 256, 0, stream>>>(bih, bhh, bsum);

    f16* hout = hs_bufs[l & 1];
    for (int t = 0; t < TT; ++t)
      step_kernel<<<256, 64, 0, stream>>>(in_seq, Kin, hout, w16ih, w16hh,
                                          bsum, t);
    in_seq = hout;
    Kin = HH;
  }

  fc_kernel<<<BB * TT / 4, 256, 0, stream>>>(in_seq, fcw, fcb, (float*)d_out);
}